// Round 10
// baseline (48.518 us; speedup 1.0000x reference)
//
#include <hip/hip_runtime.h>
#include <stdint.h>

// YOLO-style loss, faithful to the (buggy) reference _xyxy: center = w/S for both x and y.
// loss = (5*(xy+wh) + obj + 0.5*noobj) / 1024, summed over 1024*80*80 cells.
//
// R9: maximal memory-level parallelism — flat kernel, exactly ONE group (4 cells)
// per thread, grid 6400 x 256. All 10 loads issue up front (nothing to sink),
// no loop bookkeeping. Reduction atomic-free (R8's win: same-address atomics cost
// 8us per-block / 74us per-wave): block partial -> d_ws, 1-block final reduce.
// FETCH floor ~128MB is forced by the harness's 512MB inter-replay fill evicting L3.

#define S_INV (1.0f / 80.0f)

typedef float f4 __attribute__((ext_vector_type(4)));
typedef int   i4 __attribute__((ext_vector_type(4)));

__device__ __forceinline__ float cell_loss(float px, float py, float pw, float ph, float pc,
                                           float tx, float ty, float tw, float th, int m)
{
    // _xyxy (faithful to reference bug: center is w/S for BOTH axes)
    float cp = pw * S_INV;
    float ct = tw * S_INV;
    float px1 = cp - 0.5f * pw, py1 = cp - 0.5f * ph;
    float px2 = cp + 0.5f * pw, py2 = cp + 0.5f * ph;
    float tx1 = ct - 0.5f * tw, ty1 = ct - 0.5f * th;
    float tx2 = ct + 0.5f * tw, ty2 = ct + 0.5f * th;

    float iw = fmaxf(fminf(px2, tx2) - fmaxf(px1, tx1), 0.0f);
    float ih = fmaxf(fminf(py2, ty2) - fmaxf(py1, ty1), 0.0f);
    float inter = iw * ih;
    float uni = pw * ph + tw * th - inter;
    float iou = inter / uni;

    float dx = px - tx, dy = py - ty;
    float sw = sqrtf(pw) - sqrtf(tw);
    float sh = sqrtf(ph) - sqrtf(th);
    float dobj = pc - iou;

    float obj_term = 5.0f * ((dx * dx + dy * dy) + (sw * sw + sh * sh)) + dobj * dobj;
    float noobj_term = 0.5f * pc * pc;
    return (m > 0) ? obj_term : noobj_term;
}

__global__ __launch_bounds__(256) void yolo_loss_kernel(
    const f4* __restrict__ pred4,
    const f4* __restrict__ targ4,
    const i4* __restrict__ mask4,
    float* __restrict__ partials)
{
    const int gid = blockIdx.x * 256 + threadIdx.x;   // one group (4 cells) per thread

    // all 10 loads issue before any compute
    f4 p0 = pred4[5 * gid + 0];
    f4 p1 = pred4[5 * gid + 1];
    f4 p2 = pred4[5 * gid + 2];
    f4 p3 = pred4[5 * gid + 3];
    f4 p4 = pred4[5 * gid + 4];
    f4 t0 = targ4[4 * gid + 0];
    f4 t1 = targ4[4 * gid + 1];
    f4 t2 = targ4[4 * gid + 2];
    f4 t3 = targ4[4 * gid + 3];
    i4 m  = mask4[gid];

    float acc = 0.0f;
    acc += cell_loss(p0.x, p0.y, p0.z, p0.w, p1.x, t0.x, t0.y, t0.z, t0.w, m.x);
    acc += cell_loss(p1.y, p1.z, p1.w, p2.x, p2.y, t1.x, t1.y, t1.z, t1.w, m.y);
    acc += cell_loss(p2.z, p2.w, p3.x, p3.y, p3.z, t2.x, t2.y, t2.z, t2.w, m.z);
    acc += cell_loss(p3.w, p4.x, p4.y, p4.z, p4.w, t3.x, t3.y, t3.z, t3.w, m.w);

    // wave (64-lane) shuffle reduction
    #pragma unroll
    for (int off = 32; off > 0; off >>= 1)
        acc += __shfl_down(acc, off, 64);

    __shared__ float wsum[4];
    int lane = threadIdx.x & 63;
    int wid = threadIdx.x >> 6;
    if (lane == 0) wsum[wid] = acc;
    __syncthreads();

    if (threadIdx.x == 0)
        partials[blockIdx.x] = wsum[0] + wsum[1] + wsum[2] + wsum[3];   // no atomics
}

__global__ __launch_bounds__(256) void final_reduce_kernel(
    const float* __restrict__ partials, float* __restrict__ out, int n)
{
    float a = 0.0f;
    for (int i = threadIdx.x; i < n; i += 256)
        a += partials[i];

    #pragma unroll
    for (int off = 32; off > 0; off >>= 1)
        a += __shfl_down(a, off, 64);

    __shared__ float wsum[4];
    int lane = threadIdx.x & 63;
    int wid = threadIdx.x >> 6;
    if (lane == 0) wsum[wid] = a;
    __syncthreads();

    if (threadIdx.x == 0)
        out[0] = (wsum[0] + wsum[1] + wsum[2] + wsum[3]) * (1.0f / 1024.0f);
}

extern "C" void kernel_launch(void* const* d_in, const int* in_sizes, int n_in,
                              void* d_out, int out_size, void* d_ws, size_t ws_size,
                              hipStream_t stream) {
    const f4* pred4 = (const f4*)d_in[0];   // [1024,80,80,5] f32
    const f4* targ4 = (const f4*)d_in[1];   // [1024,80,80,4] f32
    const i4* mask4 = (const i4*)d_in[2];   // [1024,80,80]   i32
    float* out = (float*)d_out;
    float* partials = (float*)d_ws;         // 6400 floats = 25.6 KB (ws is larger)

    int ncells = in_sizes[2];               // 1024*80*80 = 6,553,600
    int ngroups = ncells / 4;               // 1,638,400
    int grid = ngroups / 256;               // 6400, exact

    yolo_loss_kernel<<<grid, 256, 0, stream>>>(pred4, targ4, mask4, partials);
    final_reduce_kernel<<<1, 256, 0, stream>>>(partials, out, grid);
}